// Round 11
// baseline (118.760 us; speedup 1.0000x reference)
//
#include <hip/hip_runtime.h>

typedef short s16x8 __attribute__((ext_vector_type(8)));
typedef float f32x4 __attribute__((ext_vector_type(4)));
typedef unsigned long long u64;

__device__ __forceinline__ short f2bf(float f) {  // RNE f32->bf16
  union { float f; unsigned u; } cv;
  cv.f = f;
  unsigned u = cv.u;
  u = (u + 0x7FFFu + ((u >> 16) & 1u)) >> 16;
  return (short)u;
}
// pack two f32 -> bf16x2 by truncation (low elem = lo)
__device__ __forceinline__ unsigned pk2(float lo, float hi) {
  union { float f; unsigned u; } a, b;
  a.f = lo;
  b.f = hi;
  return (a.u >> 16) | (b.u & 0xFFFF0000u);
}

// Block-wide reduce of a preloaded 64-row hist tile (8 int4/thread).
// Returns byte-packed counts for column j == t (valid for t < 128).
__device__ __forceinline__ uint2 hist_reduce(const int4* bv, int t,
                                             unsigned (&red)[4][32][4][2]) {
  const int w = t >> 6, l = t & 63;
  unsigned pA[4] = {0, 0, 0, 0}, pB[4] = {0, 0, 0, 0};
#pragma unroll
  for (int it = 0; it < 8; ++it) {
    const int vv[4] = {bv[it].x, bv[it].y, bv[it].z, bv[it].w};
#pragma unroll
    for (int jj = 0; jj < 4; ++jj) {
      pA[jj] += (unsigned)(vv[jj] == 1) + ((unsigned)(vv[jj] == 2) << 8) +
                ((unsigned)(vv[jj] == 3) << 16) + ((unsigned)(vv[jj] == 4) << 24);
      pB[jj] += (unsigned)(vv[jj] == 5);
    }
  }
#pragma unroll
  for (int jj = 0; jj < 4; ++jj) {  // lanes l, l^32 share the column set
    pA[jj] += (unsigned)__shfl_xor((int)pA[jj], 32);
    pB[jj] += (unsigned)__shfl_xor((int)pB[jj], 32);
  }
  if (l < 32) {
#pragma unroll
    for (int jj = 0; jj < 4; ++jj) {
      red[w][l][jj][0] = pA[jj];
      red[w][l][jj][1] = pB[jj];
    }
  }
  __syncthreads();
  uint2 r = make_uint2(0u, 0u);
  if (t < 128) {
    const int cc = t >> 2, jj = t & 3;
#pragma unroll
    for (int w2 = 0; w2 < 4; ++w2) {
      r.x += red[w2][cc][jj][0];
      r.y += red[w2][cc][jj][1];
    }
  }
  return r;
}

// ---------------------------------------------------------------------------
// Single fused kernel, 512 blocks x 256 thr (>=2 blocks/CU co-resident).
// Block B: b = B&255, hh = B>>8 (partner B^256 is same-XCD under %8 rr).
//  1. T0 volley: own bfm half (32KB contiguous), a_bfm, adj panel (32KB).
//  2. hist own half -> publish partial cnt (atomic u64) + flag.
//  3. blocks 0..19: compute McT table -> publish + 20-count flag.
//  4. t0 bounded-spin on partner flag + mc flag; fallback: recompute
//     partner's half locally (never taken when co-resident).
//  5. byte-add halves -> P^T scatter (XOR-swz LDS) -> Q = adj@P (8 MFMA)
//     -> wave-local transpose -> out = Mrows@Q^T (8 MFMA, f32x4 stores).
// ---------------------------------------------------------------------------
__global__ __launch_bounds__(256, 2) void fused_hs_kernel(
    const int* __restrict__ bfm, const float* __restrict__ adj,
    const int* __restrict__ a_bfm, const float* __restrict__ adj_w,
    const float* __restrict__ adj_a, unsigned* __restrict__ cflag,
    unsigned* __restrict__ mcflag, u64* __restrict__ cnt_h,
    unsigned short* __restrict__ McT, float* __restrict__ out) {
  __shared__ unsigned red[4][32][4][2];                     // 4 KB
  __shared__ float As[5][128];                              // 2.5 KB
  __shared__ __align__(16) unsigned short Pt[32 * 128];     // 8 KB, XOR-swz
  __shared__ __align__(16) unsigned short Mt[128 * 40];     // 10 KB
  __shared__ __align__(16) unsigned short Qs[4 * 16 * 40];  // 5 KB
  __shared__ int okflag;

  const int bid = blockIdx.x;
  const int b = bid & 255, hh = bid >> 8;
  const int t = threadIdx.x, w = t >> 6, l = t & 63, g = l >> 4, c = l & 15;
  const int row0 = hh * 64 + w * 16;

  // ---- T0 volley: bfm half, a_bfm, adj panel (issue order = consumption) ---
  const int4* bp = (const int4*)bfm + (size_t)b * 4096 + hh * 2048;
  int4 bv[8];
#pragma unroll
  for (int it = 0; it < 8; ++it) bv[it] = bp[it * 256 + t];
  int av = 0;
  if (t < 128) av = a_bfm[b * 128 + t];
  const float* arow = adj + (size_t)b * 16384 + (size_t)(row0 + c) * 128;
  float4 a0[4], a1[4];
#pragma unroll
  for (int kk = 0; kk < 4; ++kk) {
    a0[kk] = *(const float4*)(arow + kk * 32 + g * 8);
    a1[kk] = *(const float4*)(arow + kk * 32 + g * 8 + 4);
  }
  ((uint4*)Pt)[t] = make_uint4(0u, 0u, 0u, 0u);
  ((uint4*)Pt)[256 + t] = make_uint4(0u, 0u, 0u, 0u);  // 512 uint4 = 8 KB

  // ---- hist own half; publish partial ----
  const uint2 own = hist_reduce(bv, t, red);
  if (t < 128) {
    const u64 myv = ((u64)own.y << 32) | (u64)own.x;
    __hip_atomic_store(&cnt_h[(b * 2 + hh) * 128 + t], myv, __ATOMIC_RELEASE,
                       __HIP_MEMORY_SCOPE_AGENT);
  }
  __threadfence();
  __syncthreads();
  if (t == 0) atomicAdd(&cflag[b], 1u);

  // ---- McT table (blocks 0..19 only) ----
  if (bid < 20) {
    const int e = bid >> 2, mg = bid & 3;
    for (int idx = t; idx < 640; idx += 256)
      As[idx >> 7][idx & 127] = adj_a[idx];
    __syncthreads();
    const int m = mg * 32 + (t >> 3), ns = t & 7;
    const float* W = adj_w + (size_t)e * 16384 + (size_t)m * 128 + ns * 16;
    float acc[5] = {0.f, 0.f, 0.f, 0.f, 0.f};
#pragma unroll
    for (int it = 0; it < 4; ++it) {
      const float4 wv = *(const float4*)(W + it * 4);
      const float wa[4] = {wv.x, wv.y, wv.z, wv.w};
#pragma unroll
      for (int q = 0; q < 4; ++q) {
        const int n = ns * 16 + it * 4 + q;
#pragma unroll
        for (int a = 0; a < 5; ++a) acc[a] = fmaf(wa[q], As[a][n], acc[a]);
      }
    }
#pragma unroll
    for (int d = 1; d < 8; d <<= 1)
#pragma unroll
      for (int a = 0; a < 5; ++a) acc[a] += __shfl_xor(acc[a], d);
    if (ns == 0) {
#pragma unroll
      for (int a = 0; a < 5; ++a)
        McT[m * 40 + e * 5 + a] = (unsigned short)f2bf(acc[a]);
      if (e == 0)
#pragma unroll
        for (int r = 25; r < 40; ++r) McT[m * 40 + r] = 0;
    }
    __threadfence();
    __syncthreads();
    if (t == 0) atomicAdd(mcflag, 1u);
  }

  // ---- t0 bounded spin: partner cnt + McT table ----
  if (t == 0) {
    unsigned itc = 0;
    while (__hip_atomic_load(&cflag[b], __ATOMIC_ACQUIRE,
                             __HIP_MEMORY_SCOPE_AGENT) < 2u &&
           itc < (1u << 20))
      ++itc;
    okflag = (__hip_atomic_load(&cflag[b], __ATOMIC_ACQUIRE,
                                __HIP_MEMORY_SCOPE_AGENT) >= 2u);
    unsigned itm = 0;
    while (__hip_atomic_load(mcflag, __ATOMIC_ACQUIRE,
                             __HIP_MEMORY_SCOPE_AGENT) < 20u &&
           itm < (1u << 22))
      ++itm;
  }
  __syncthreads();

  // ---- partner counts: fast path = atomic read; fallback = recompute ----
  unsigned cxp = 0, cyp = 0;
  if (okflag) {
    __threadfence();
    if (t < 128) {
      const u64 v = __hip_atomic_load(&cnt_h[(b * 2 + (1 - hh)) * 128 + t],
                                      __ATOMIC_RELAXED,
                                      __HIP_MEMORY_SCOPE_AGENT);
      cxp = (unsigned)v;
      cyp = (unsigned)(v >> 32);
    }
  } else {
    int4 bv2[8];
    const int4* bp2 = (const int4*)bfm + (size_t)b * 4096 + (1 - hh) * 2048;
#pragma unroll
    for (int it = 0; it < 8; ++it) bv2[it] = bp2[it * 256 + t];
    const uint2 pc = hist_reduce(bv2, t, red);
    cxp = pc.x;
    cyp = pc.y;
  }

  // ---- Mt staging: L2-bypassing u64 atomic loads (1280 u64 total) ----
  {
    u64* mtd = (u64*)Mt;
    const u64* mcs = (const u64*)McT;
#pragma unroll
    for (int i = 0; i < 5; ++i)
      mtd[i * 256 + t] = __hip_atomic_load(&mcs[i * 256 + t], __ATOMIC_RELAXED,
                                           __HIP_MEMORY_SCOPE_AGENT);
  }

  // ---- P^T scatter: Pt[r][j=t] = cnt_e(j), r=(e-1)*5+ai, XOR-swz chunks ----
  if (t < 128 && av > 0) {
    const unsigned cx = own.x + cxp;  // byte-packed add, bytes <= 128
    const unsigned cy = own.y + cyp;
    const int ai = av - 1;
    const int chunk = t >> 3, off = t & 7;
    const float cf[5] = {(float)(cx & 255u), (float)((cx >> 8) & 255u),
                         (float)((cx >> 16) & 255u), (float)(cx >> 24),
                         (float)(cy & 255u)};
#pragma unroll
    for (int ei = 0; ei < 5; ++ei) {
      const int r = ei * 5 + ai;
      Pt[r * 128 + ((chunk ^ (r & 15)) << 3) + off] =
          (unsigned short)f2bf(cf[ei]);
    }
  }
  asm volatile("s_waitcnt lgkmcnt(0)" ::: "memory");
  __builtin_amdgcn_s_barrier();

  // ---- stage 1: Q = adj @ P  (2 col-tiles x 4 k-chunks = 8 MFMA) ----
  s16x8 bP[4][2];
#pragma unroll
  for (int kk = 0; kk < 4; ++kk)
#pragma unroll
    for (int ct = 0; ct < 2; ++ct) {
      const int r = ct * 16 + c;
      bP[kk][ct] =
          *(const s16x8*)&Pt[r * 128 + (((kk * 4 + g) ^ (r & 15)) << 3)];
    }
  s16x8 apk[4];
#pragma unroll
  for (int kk = 0; kk < 4; ++kk) {
    unsigned* pu = (unsigned*)&apk[kk];
    pu[0] = pk2(a0[kk].x, a0[kk].y);
    pu[1] = pk2(a0[kk].z, a0[kk].w);
    pu[2] = pk2(a1[kk].x, a1[kk].y);
    pu[3] = pk2(a1[kk].z, a1[kk].w);
  }
  f32x4 accQ[2] = {{0.f, 0.f, 0.f, 0.f}, {0.f, 0.f, 0.f, 0.f}};
#pragma unroll
  for (int kk = 0; kk < 4; ++kk)
#pragma unroll
    for (int ct = 0; ct < 2; ++ct)
      accQ[ct] = __builtin_amdgcn_mfma_f32_16x16x32_bf16(apk[kk], bP[kk][ct],
                                                         accQ[ct], 0, 0, 0);

  // ---- transpose Q through wave-local LDS (no cross-wave barrier) ----
  unsigned short* qsw = &Qs[w * 16 * 40];
#pragma unroll
  for (int ct = 0; ct < 2; ++ct)
#pragma unroll
    for (int q = 0; q < 4; ++q)
      qsw[(g * 4 + q) * 40 + ct * 16 + c] = (unsigned short)f2bf(accQ[ct][q]);
  const s16x8 aQ = *(const s16x8*)&qsw[c * 40 + g * 8];

  // ---- stage 2 (operand-swapped): lane (g,c) -> out[row0+c][mt*16+g*4..+3]
  float* ob = out + (size_t)b * 16384 + (size_t)(row0 + c) * 128;
#pragma unroll
  for (int mt = 0; mt < 8; ++mt) {
    const s16x8 aM = *(const s16x8*)&Mt[(mt * 16 + c) * 40 + g * 8];
    f32x4 acc2 = {0.f, 0.f, 0.f, 0.f};
    acc2 = __builtin_amdgcn_mfma_f32_16x16x32_bf16(aM, aQ, acc2, 0, 0, 0);
    *(f32x4*)(ob + mt * 16 + g * 4) = acc2;
  }
}

extern "C" void kernel_launch(void* const* d_in, const int* in_sizes, int n_in,
                              void* d_out, int out_size, void* d_ws,
                              size_t ws_size, hipStream_t stream) {
  // inputs: 0=afm(unused), 1=bfm, 2=a_bfm, 3=adj, 4=adj_w, 5=adj_a
  const int* bfm = (const int*)d_in[1];
  const int* a_bfm = (const int*)d_in[2];
  const float* adj = (const float*)d_in[3];
  const float* adj_w = (const float*)d_in[4];
  const float* adj_a = (const float*)d_in[5];
  float* out = (float*)d_out;

  unsigned* cflag = (unsigned*)d_ws;                        // 256 u32
  unsigned* mcflag = (unsigned*)((char*)d_ws + 1024);       // 1 u32
  u64* cnt_h = (u64*)((char*)d_ws + 4096);                  // 512*128*8B=512KB
  unsigned short* McT =
      (unsigned short*)((char*)d_ws + 4096 + 512 * 1024);   // 10.24 KB

  hipMemsetAsync(d_ws, 0, 2048, stream);  // zero flags (graph-capturable)
  fused_hs_kernel<<<dim3(512), dim3(256), 0, stream>>>(
      bfm, adj, a_bfm, adj_w, adj_a, cflag, mcflag, cnt_h, McT, out);
}

// Round 12
// 21.096 us; speedup vs baseline: 5.6296x; 5.6296x over previous
//
#include <hip/hip_runtime.h>

typedef short s16x8 __attribute__((ext_vector_type(8)));
typedef float f32x4 __attribute__((ext_vector_type(4)));

__device__ __forceinline__ short f2bf(float f) {  // RNE f32->bf16
  union { float f; unsigned u; } cv;
  cv.f = f;
  unsigned u = cv.u;
  u = (u + 0x7FFFu + ((u >> 16) & 1u)) >> 16;
  return (short)u;
}
// pack two f32 -> bf16x2 by truncation (low elem = lo)
__device__ __forceinline__ unsigned pk2(float lo, float hi) {
  union { float f; unsigned u; } a, b;
  a.f = lo;
  b.f = hi;
  return (a.u >> 16) | (b.u & 0xFFFF0000u);
}

// ---------------------------------------------------------------------------
// K0: McT[m*40 + e*5 + a] = bf16(sum_n adj_w[e,m,n]*adj_a[a,n]); rows
// [25,40) zeroed by e==0 blocks. 80 blocks x 256 threads (r10-proven).
// ---------------------------------------------------------------------------
__global__ __launch_bounds__(256) void precomp_McT(
    const float* __restrict__ adj_w, const float* __restrict__ adj_a,
    unsigned short* __restrict__ McT) {
  __shared__ float As[5][128];
  const int t = threadIdx.x;
  const int e = blockIdx.x >> 4, mg = blockIdx.x & 15;
  for (int idx = t; idx < 640; idx += 256) As[idx >> 7][idx & 127] = adj_a[idx];
  __syncthreads();
  const int m = mg * 8 + (t >> 5), l2 = t & 31;
  const float4 wv = *(const float4*)(adj_w + (size_t)e * 16384 +
                                     (size_t)m * 128 + l2 * 4);
  const float wa[4] = {wv.x, wv.y, wv.z, wv.w};
  float acc[5] = {0.f, 0.f, 0.f, 0.f, 0.f};
#pragma unroll
  for (int q = 0; q < 4; ++q) {
    const int n = l2 * 4 + q;
#pragma unroll
    for (int a = 0; a < 5; ++a) acc[a] = fmaf(wa[q], As[a][n], acc[a]);
  }
#pragma unroll
  for (int d = 1; d < 32; d <<= 1)
#pragma unroll
    for (int a = 0; a < 5; ++a) acc[a] += __shfl_xor(acc[a], d);
  if (l2 == 0) {
#pragma unroll
    for (int a = 0; a < 5; ++a)
      McT[m * 40 + e * 5 + a] = (unsigned short)f2bf(acc[a]);
    if (e == 0)
#pragma unroll
      for (int r = 25; r < 40; ++r) McT[m * 40 + r] = 0;
  }
}

// ---------------------------------------------------------------------------
// Main: block B -> (b = B&255, hh = B>>8); pair B/B+256 shares XCD -> the
// duplicated full-bfm[b] read hits L2. 512 blocks x 256 thr = 2 blocks/CU.
//   T0: bfm[b] full (16 int4), McT, a_bfm, adj panel (8 float4).
//   full hist (register byte counters, shfl, LDS reduce) -> P^T scatter
//   (XOR-swz LDS) -> Q = adj@P (8 MFMA) -> wave-local transpose ->
//   out = Mrows@Q^T (8 MFMA, operand-swapped -> float4 stores).
// ---------------------------------------------------------------------------
__global__ __launch_bounds__(256, 2) void fused_full_kernel(
    const int* __restrict__ bfm, const float* __restrict__ adj,
    const int* __restrict__ a_bfm, const unsigned short* __restrict__ McT,
    float* __restrict__ out) {
  __shared__ unsigned red[4][32][4][2];                     // 4 KB
  __shared__ __align__(16) unsigned short Pt[32 * 128];     // 8 KB, XOR-swz
  __shared__ __align__(16) unsigned short Mt[128 * 40];     // 10 KB
  __shared__ __align__(16) unsigned short Qs[4 * 16 * 40];  // 5 KB

  const int bid = blockIdx.x;
  const int b = bid & 255, hh = bid >> 8;
  const int t = threadIdx.x, w = t >> 6, l = t & 63, g = l >> 4, c = l & 15;
  const int row0 = hh * 64 + w * 16;

  // ---- T0 volley (issue order = consumption order) ----
  const int4* bp = (const int4*)bfm + (size_t)b * 4096;
  int4 bv[16];
#pragma unroll
  for (int it = 0; it < 16; ++it) bv[it] = bp[it * 256 + t];
  s16x8 mst0 = *(const s16x8*)&McT[t * 8];
  s16x8 mst1 = *(const s16x8*)&McT[(256 + t) * 8];
  s16x8 mst2 = {0, 0, 0, 0, 0, 0, 0, 0};
  if (t < 128) mst2 = *(const s16x8*)&McT[(512 + t) * 8];
  int av = 0;
  if (t < 128) av = a_bfm[b * 128 + t];
  const float* arow = adj + (size_t)b * 16384 + (size_t)(row0 + c) * 128;
  float4 a0[4], a1[4];
#pragma unroll
  for (int kk = 0; kk < 4; ++kk) {
    a0[kk] = *(const float4*)(arow + kk * 32 + g * 8);
    a1[kk] = *(const float4*)(arow + kk * 32 + g * 8 + 4);
  }

  // ---- Pt zero (no global dep) ----
  ((uint4*)Pt)[t] = make_uint4(0u, 0u, 0u, 0u);
  ((uint4*)Pt)[256 + t] = make_uint4(0u, 0u, 0u, 0u);

  // ---- full histogram: thread covers col4 = t&31, rows it*8 + (t>>5) ----
  unsigned pA[4] = {0, 0, 0, 0}, pB[4] = {0, 0, 0, 0};
#pragma unroll
  for (int it = 0; it < 16; ++it) {
    const int vv[4] = {bv[it].x, bv[it].y, bv[it].z, bv[it].w};
#pragma unroll
    for (int jj = 0; jj < 4; ++jj) {
      pA[jj] += (unsigned)(vv[jj] == 1) + ((unsigned)(vv[jj] == 2) << 8) +
                ((unsigned)(vv[jj] == 3) << 16) + ((unsigned)(vv[jj] == 4) << 24);
      pB[jj] += (unsigned)(vv[jj] == 5);  // per-byte <= 16
    }
  }
#pragma unroll
  for (int jj = 0; jj < 4; ++jj) {  // lanes l, l^32 share the column set
    pA[jj] += (unsigned)__shfl_xor((int)pA[jj], 32);
    pB[jj] += (unsigned)__shfl_xor((int)pB[jj], 32);
  }
  if (l < 32) {
#pragma unroll
    for (int jj = 0; jj < 4; ++jj) {
      red[w][l][jj][0] = pA[jj];  // per-byte <= 32
      red[w][l][jj][1] = pB[jj];
    }
  }
  // Mt stage (vmcnt waits only through mst; adj stays queued)
  *(s16x8*)&Mt[t * 8] = mst0;
  *(s16x8*)&Mt[(256 + t) * 8] = mst1;
  if (t < 128) *(s16x8*)&Mt[(512 + t) * 8] = mst2;
  asm volatile("s_waitcnt lgkmcnt(0)" ::: "memory");
  __builtin_amdgcn_s_barrier();

  // ---- final reduce + P^T scatter, all in-LDS (column j == t, t<128) ----
  if (t < 128 && av > 0) {
    unsigned A = 0, B = 0;
    const int cc = t >> 2, jj = t & 3;
#pragma unroll
    for (int w2 = 0; w2 < 4; ++w2) {
      A += red[w2][cc][jj][0];  // per-byte <= 128, no carry
      B += red[w2][cc][jj][1];
    }
    const int ai = av - 1;
    const int chunk = t >> 3, off = t & 7;
    const float cf[5] = {(float)(A & 255u), (float)((A >> 8) & 255u),
                         (float)((A >> 16) & 255u), (float)(A >> 24),
                         (float)(B & 255u)};
#pragma unroll
    for (int ei = 0; ei < 5; ++ei) {
      const int r = ei * 5 + ai;
      Pt[r * 128 + ((chunk ^ (r & 15)) << 3) + off] =
          (unsigned short)f2bf(cf[ei]);
    }
  }
  asm volatile("s_waitcnt lgkmcnt(0)" ::: "memory");
  __builtin_amdgcn_s_barrier();

  // ---- stage 1: Q = adj @ P  (2 col-tiles x 4 k-chunks = 8 MFMA) ----
  s16x8 bP[4][2];
#pragma unroll
  for (int kk = 0; kk < 4; ++kk)
#pragma unroll
    for (int ct = 0; ct < 2; ++ct) {
      const int r = ct * 16 + c;
      bP[kk][ct] =
          *(const s16x8*)&Pt[r * 128 + (((kk * 4 + g) ^ (r & 15)) << 3)];
    }
  // pack adj A-frags (vmcnt(0) lands here; issued at T0, covered by hist)
  s16x8 apk[4];
#pragma unroll
  for (int kk = 0; kk < 4; ++kk) {
    unsigned* pu = (unsigned*)&apk[kk];
    pu[0] = pk2(a0[kk].x, a0[kk].y);
    pu[1] = pk2(a0[kk].z, a0[kk].w);
    pu[2] = pk2(a1[kk].x, a1[kk].y);
    pu[3] = pk2(a1[kk].z, a1[kk].w);
  }
  f32x4 accQ[2] = {{0.f, 0.f, 0.f, 0.f}, {0.f, 0.f, 0.f, 0.f}};
#pragma unroll
  for (int kk = 0; kk < 4; ++kk)
#pragma unroll
    for (int ct = 0; ct < 2; ++ct)
      accQ[ct] = __builtin_amdgcn_mfma_f32_16x16x32_bf16(apk[kk], bP[kk][ct],
                                                         accQ[ct], 0, 0, 0);

  // ---- transpose Q through wave-local LDS (no cross-wave barrier) ----
  unsigned short* qsw = &Qs[w * 16 * 40];
#pragma unroll
  for (int ct = 0; ct < 2; ++ct)
#pragma unroll
    for (int q = 0; q < 4; ++q)
      qsw[(g * 4 + q) * 40 + ct * 16 + c] = (unsigned short)f2bf(accQ[ct][q]);
  const s16x8 aQ = *(const s16x8*)&qsw[c * 40 + g * 8];

  // ---- stage 2 (operand-swapped): lane (g,c) -> out[row0+c][mt*16+g*4..+3]
  float* ob = out + (size_t)b * 16384 + (size_t)(row0 + c) * 128;
#pragma unroll
  for (int mt = 0; mt < 8; ++mt) {
    const s16x8 aM = *(const s16x8*)&Mt[(mt * 16 + c) * 40 + g * 8];
    f32x4 acc2 = {0.f, 0.f, 0.f, 0.f};
    acc2 = __builtin_amdgcn_mfma_f32_16x16x32_bf16(aM, aQ, acc2, 0, 0, 0);
    *(f32x4*)(ob + mt * 16 + g * 4) = acc2;
  }
}

extern "C" void kernel_launch(void* const* d_in, const int* in_sizes, int n_in,
                              void* d_out, int out_size, void* d_ws,
                              size_t ws_size, hipStream_t stream) {
  // inputs: 0=afm(unused), 1=bfm, 2=a_bfm, 3=adj, 4=adj_w, 5=adj_a
  const int* bfm = (const int*)d_in[1];
  const int* a_bfm = (const int*)d_in[2];
  const float* adj = (const float*)d_in[3];
  const float* adj_w = (const float*)d_in[4];
  const float* adj_a = (const float*)d_in[5];
  float* out = (float*)d_out;

  unsigned short* McT = (unsigned short*)d_ws;  // 128*40 bf16 = 10.24 KB

  precomp_McT<<<dim3(80), dim3(256), 0, stream>>>(adj_w, adj_a, McT);
  fused_full_kernel<<<dim3(512), dim3(256), 0, stream>>>(bfm, adj, a_bfm, McT,
                                                         out);
}

// Round 13
// 18.624 us; speedup vs baseline: 6.3766x; 1.1327x over previous
//
#include <hip/hip_runtime.h>

typedef short s16x8 __attribute__((ext_vector_type(8)));
typedef float f32x4 __attribute__((ext_vector_type(4)));

__device__ __forceinline__ short f2bf(float f) {  // RNE f32->bf16
  union { float f; unsigned u; } cv;
  cv.f = f;
  unsigned u = cv.u;
  u = (u + 0x7FFFu + ((u >> 16) & 1u)) >> 16;
  return (short)u;
}
// pack two f32 -> bf16x2 by truncation (low elem = lo)
__device__ __forceinline__ unsigned pk2(float lo, float hi) {
  union { float f; unsigned u; } a, b;
  a.f = lo;
  b.f = hi;
  return (a.u >> 16) | (b.u & 0xFFFF0000u);
}

// ---------------------------------------------------------------------------
// K1: blocks 0..79   = McT table, 80-way (e x 16 mgroups; 32KB adj_w each):
//     McT[m*40 + e*5 + a] = bf16(sum_n W[e,m,n]*A[a,n]); rows [25,40) zeroed.
//     blocks 80..1103 = histogram quarter (b, qq): contiguous 16KB read,
//     partial counts -> cnt_q[b*512 + j*4 + qq] (uint2, byte-packed, <=32).
// ---------------------------------------------------------------------------
__global__ __launch_bounds__(256, 4) void hist_mc_kernel(
    const int* __restrict__ bfm, const float* __restrict__ adj_w,
    const float* __restrict__ adj_a, uint2* __restrict__ cnt_q,
    unsigned short* __restrict__ McT) {
  __shared__ unsigned red[4][32][4][2];
  __shared__ float As[5][128];
  const int t = threadIdx.x;

  if (blockIdx.x < 80) {  // ---- McT blocks (r12-proven body) ----
    const int e = blockIdx.x >> 4, mg = blockIdx.x & 15;
    for (int idx = t; idx < 640; idx += 256)
      As[idx >> 7][idx & 127] = adj_a[idx];
    __syncthreads();
    const int m = mg * 8 + (t >> 5), l2 = t & 31;
    const float4 wv = *(const float4*)(adj_w + (size_t)e * 16384 +
                                       (size_t)m * 128 + l2 * 4);
    const float wa[4] = {wv.x, wv.y, wv.z, wv.w};
    float acc[5] = {0.f, 0.f, 0.f, 0.f, 0.f};
#pragma unroll
    for (int q = 0; q < 4; ++q) {
      const int n = l2 * 4 + q;
#pragma unroll
      for (int a = 0; a < 5; ++a) acc[a] = fmaf(wa[q], As[a][n], acc[a]);
    }
#pragma unroll
    for (int d = 1; d < 32; d <<= 1)
#pragma unroll
      for (int a = 0; a < 5; ++a) acc[a] += __shfl_xor(acc[a], d);
    if (l2 == 0) {
#pragma unroll
      for (int a = 0; a < 5; ++a)
        McT[m * 40 + e * 5 + a] = (unsigned short)f2bf(acc[a]);
      if (e == 0)
#pragma unroll
        for (int r = 25; r < 40; ++r) McT[m * 40 + r] = 0;
    }
    return;
  }

  // ---- hist quarter blocks: contiguous 16KB read ----
  const int idx2 = blockIdx.x - 80;
  const int b = idx2 >> 2, qq = idx2 & 3;
  const int w = t >> 6, l = t & 63;
  const int4* bp = (const int4*)bfm + (size_t)b * 4096 + qq * 1024;
  unsigned pA[4] = {0, 0, 0, 0}, pB[4] = {0, 0, 0, 0};
#pragma unroll
  for (int it = 0; it < 4; ++it) {
    const int4 v = bp[it * 256 + t];  // rows qq*32 + it*8 + (t>>5)
    const int vv[4] = {v.x, v.y, v.z, v.w};
#pragma unroll
    for (int jj = 0; jj < 4; ++jj) {  // cols (t&31)*4 + jj
      pA[jj] += (unsigned)(vv[jj] == 1) + ((unsigned)(vv[jj] == 2) << 8) +
                ((unsigned)(vv[jj] == 3) << 16) + ((unsigned)(vv[jj] == 4) << 24);
      pB[jj] += (unsigned)(vv[jj] == 5);  // per-byte <= 4
    }
  }
#pragma unroll
  for (int jj = 0; jj < 4; ++jj) {  // lanes l, l^32 share the column set
    pA[jj] += (unsigned)__shfl_xor((int)pA[jj], 32);
    pB[jj] += (unsigned)__shfl_xor((int)pB[jj], 32);
  }
  if (l < 32) {
#pragma unroll
    for (int jj = 0; jj < 4; ++jj) {
      red[w][l][jj][0] = pA[jj];  // per-byte <= 8
      red[w][l][jj][1] = pB[jj];
    }
  }
  __syncthreads();
  if (t < 128) {
    unsigned A = 0, B = 0;
    const int cc = t >> 2, jj = t & 3;
#pragma unroll
    for (int w2 = 0; w2 < 4; ++w2) {
      A += red[w2][cc][jj][0];  // per-byte <= 32
      B += red[w2][cc][jj][1];
    }
    cnt_q[(size_t)b * 512 + t * 4 + qq] = make_uint2(A, B);
  }
}

// ---------------------------------------------------------------------------
// K2: out[b, hh*64 .. +64, :] = (adj@P) @ McT, two skinny MFMA stages.
// 512 blocks (b, half) x 256 threads, ~23 KB LDS, 2 blocks/CU.
// adj loads issued at T0 into registers; lgkmcnt-only waits + raw s_barrier
// keep them in flight until the pack. Stage-2 operand-swapped (r10/r12-
// proven) -> f32x4 coalesced stores.
// ---------------------------------------------------------------------------
__global__ __launch_bounds__(256, 2) void skinny_kernel(
    const float* __restrict__ adj, const int* __restrict__ a_bfm,
    const uint2* __restrict__ cnt_q, const unsigned short* __restrict__ McT,
    float* __restrict__ out) {
  __shared__ __align__(16) unsigned short Pt[32 * 128];     // 8 KB, XOR-swz
  __shared__ __align__(16) unsigned short Mt[128 * 40];     // 10 KB
  __shared__ __align__(16) unsigned short Qs[4 * 16 * 40];  // 5 KB
  const int bh = blockIdx.x, b = bh >> 1, hh = bh & 1;
  const int t = threadIdx.x, w = t >> 6, l = t & 63, g = l >> 4, c = l & 15;
  const int row0 = hh * 64 + w * 16;

  // ---- T0: small loads first (consumed first), adj last (consumed last) ----
  uint4 ca = make_uint4(0u, 0u, 0u, 0u), cb = make_uint4(0u, 0u, 0u, 0u);
  int av = 0;
  if (t < 128) {
    const uint4* cp = (const uint4*)(cnt_q + (size_t)b * 512 + t * 4);
    ca = cp[0];  // partials qq=0,1
    cb = cp[1];  // partials qq=2,3
    av = a_bfm[b * 128 + t];
  }
  s16x8 mst0 = *(const s16x8*)&McT[t * 8];
  s16x8 mst1 = *(const s16x8*)&McT[(256 + t) * 8];
  s16x8 mst2 = {0, 0, 0, 0, 0, 0, 0, 0};
  if (t < 128) mst2 = *(const s16x8*)&McT[(512 + t) * 8];
  const float* arow = adj + (size_t)b * 16384 + (size_t)(row0 + c) * 128;
  float4 a0[4], a1[4];
#pragma unroll
  for (int kk = 0; kk < 4; ++kk) {
    a0[kk] = *(const float4*)(arow + kk * 32 + g * 8);
    a1[kk] = *(const float4*)(arow + kk * 32 + g * 8 + 4);
  }

  // ---- zero Pt; stage Mt (vmcnt waits only to mst; adj stays queued) ----
  ((uint4*)Pt)[t] = make_uint4(0u, 0u, 0u, 0u);
  ((uint4*)Pt)[256 + t] = make_uint4(0u, 0u, 0u, 0u);
  *(s16x8*)&Mt[t * 8] = mst0;
  *(s16x8*)&Mt[(256 + t) * 8] = mst1;
  if (t < 128) *(s16x8*)&Mt[(512 + t) * 8] = mst2;
  asm volatile("s_waitcnt lgkmcnt(0)" ::: "memory");
  __builtin_amdgcn_s_barrier();

  // ---- scatter P^T: Pt[r][j=t] = cnt_e(j), r=(e-1)*5+ai, XOR-swz chunks ----
  if (t < 128 && av > 0) {
    const unsigned cx = ca.x + ca.z + cb.x + cb.z;  // byte-packed, <=128
    const unsigned cy = ca.y + ca.w + cb.y + cb.w;
    const int ai = av - 1;
    const int chunk = t >> 3, off = t & 7;
    const float cf[5] = {(float)(cx & 255u), (float)((cx >> 8) & 255u),
                         (float)((cx >> 16) & 255u), (float)(cx >> 24),
                         (float)(cy & 255u)};
#pragma unroll
    for (int ei = 0; ei < 5; ++ei) {
      const int r = ei * 5 + ai;
      Pt[r * 128 + ((chunk ^ (r & 15)) << 3) + off] =
          (unsigned short)f2bf(cf[ei]);
    }
  }
  asm volatile("s_waitcnt lgkmcnt(0)" ::: "memory");
  __builtin_amdgcn_s_barrier();

  // ---- stage 1: Q = adj @ P  (2 col-tiles x 4 k-chunks = 8 MFMA) ----
  s16x8 bP[4][2];
#pragma unroll
  for (int kk = 0; kk < 4; ++kk)
#pragma unroll
    for (int ct = 0; ct < 2; ++ct) {
      const int r = ct * 16 + c;
      bP[kk][ct] =
          *(const s16x8*)&Pt[r * 128 + (((kk * 4 + g) ^ (r & 15)) << 3)];
    }
  // pack adj A-frags (vmcnt(0) lands here; loads issued at T0, well covered)
  s16x8 apk[4];
#pragma unroll
  for (int kk = 0; kk < 4; ++kk) {
    unsigned* pu = (unsigned*)&apk[kk];
    pu[0] = pk2(a0[kk].x, a0[kk].y);
    pu[1] = pk2(a0[kk].z, a0[kk].w);
    pu[2] = pk2(a1[kk].x, a1[kk].y);
    pu[3] = pk2(a1[kk].z, a1[kk].w);
  }
  f32x4 accQ[2] = {{0.f, 0.f, 0.f, 0.f}, {0.f, 0.f, 0.f, 0.f}};
#pragma unroll
  for (int kk = 0; kk < 4; ++kk)
#pragma unroll
    for (int ct = 0; ct < 2; ++ct)
      accQ[ct] = __builtin_amdgcn_mfma_f32_16x16x32_bf16(apk[kk], bP[kk][ct],
                                                         accQ[ct], 0, 0, 0);

  // ---- transpose Q through wave-local LDS (no cross-wave barrier) ----
  unsigned short* qsw = &Qs[w * 16 * 40];
#pragma unroll
  for (int ct = 0; ct < 2; ++ct)
#pragma unroll
    for (int q = 0; q < 4; ++q)
      qsw[(g * 4 + q) * 40 + ct * 16 + c] = (unsigned short)f2bf(accQ[ct][q]);
  const s16x8 aQ = *(const s16x8*)&qsw[c * 40 + g * 8];

  // ---- stage 2 (operand-swapped): lane (g,c) -> out[row0+c][mt*16+g*4..+3]
  float* ob = out + (size_t)b * 16384 + (size_t)(row0 + c) * 128;
#pragma unroll
  for (int mt = 0; mt < 8; ++mt) {
    const s16x8 aM = *(const s16x8*)&Mt[(mt * 16 + c) * 40 + g * 8];
    f32x4 acc2 = {0.f, 0.f, 0.f, 0.f};
    acc2 = __builtin_amdgcn_mfma_f32_16x16x32_bf16(aM, aQ, acc2, 0, 0, 0);
    *(f32x4*)(ob + mt * 16 + g * 4) = acc2;
  }
}

extern "C" void kernel_launch(void* const* d_in, const int* in_sizes, int n_in,
                              void* d_out, int out_size, void* d_ws,
                              size_t ws_size, hipStream_t stream) {
  // inputs: 0=afm(unused), 1=bfm, 2=a_bfm, 3=adj, 4=adj_w, 5=adj_a
  const int* bfm = (const int*)d_in[1];
  const int* a_bfm = (const int*)d_in[2];
  const float* adj = (const float*)d_in[3];
  const float* adj_w = (const float*)d_in[4];
  const float* adj_a = (const float*)d_in[5];
  float* out = (float*)d_out;

  unsigned short* McT = (unsigned short*)d_ws;   // 128*40 bf16 = 10.24 KB
  uint2* cnt_q = (uint2*)((char*)d_ws + 16384);  // 256*512*8B = 1 MB

  hist_mc_kernel<<<dim3(1104), dim3(256), 0, stream>>>(bfm, adj_w, adj_a,
                                                       cnt_q, McT);
  skinny_kernel<<<dim3(512), dim3(256), 0, stream>>>(adj, a_bfm, cnt_q, McT,
                                                     out);
}

// Round 14
// 18.029 us; speedup vs baseline: 6.5873x; 1.0330x over previous
//
#include <hip/hip_runtime.h>

typedef short s16x8 __attribute__((ext_vector_type(8)));
typedef float f32x4 __attribute__((ext_vector_type(4)));

__device__ __forceinline__ short f2bf(float f) {  // RNE f32->bf16
  union { float f; unsigned u; } cv;
  cv.f = f;
  unsigned u = cv.u;
  u = (u + 0x7FFFu + ((u >> 16) & 1u)) >> 16;
  return (short)u;
}
// pack two f32 -> bf16x2 by truncation (low elem = lo)
__device__ __forceinline__ unsigned pk2(float lo, float hi) {
  union { float f; unsigned u; } a, b;
  a.f = lo;
  b.f = hi;
  return (a.u >> 16) | (b.u & 0xFFFF0000u);
}

// ---------------------------------------------------------------------------
// K1 (r8-proven, verbatim): blocks 0..19 = McT table (transposed):
//   McT[m*40 + e*5 + a] = bf16(sum_n W[e,m,n]*A[a,n]); rows [25,40) zeroed.
// blocks 20..531 = histogram (b, row-half): contiguous 32KB read, partial
//   counts -> cnt_h[(b*2+h)*128 + j] (uint2, byte-packed, <=64).
// ---------------------------------------------------------------------------
__global__ __launch_bounds__(256, 4) void hist_mc_kernel(
    const int* __restrict__ bfm, const float* __restrict__ adj_w,
    const float* __restrict__ adj_a, uint2* __restrict__ cnt_h,
    unsigned short* __restrict__ McT) {
  __shared__ unsigned red[4][32][4][2];
  __shared__ float As[5][128];
  const int t = threadIdx.x;

  if (blockIdx.x < 20) {  // ---- McT blocks ----
    const int bi = blockIdx.x;
    const int e = bi >> 2, mg = bi & 3;
    for (int idx = t; idx < 640; idx += 256) As[idx >> 7][idx & 127] = adj_a[idx];
    __syncthreads();
    const int m = mg * 32 + (t >> 3), ns = t & 7;
    const float* W = adj_w + (size_t)e * 16384 + (size_t)m * 128 + ns * 16;
    float acc[5] = {0.f, 0.f, 0.f, 0.f, 0.f};
#pragma unroll
    for (int it = 0; it < 4; ++it) {
      const float4 wv = *(const float4*)(W + it * 4);
      const float wa[4] = {wv.x, wv.y, wv.z, wv.w};
#pragma unroll
      for (int q = 0; q < 4; ++q) {
        const int n = ns * 16 + it * 4 + q;
#pragma unroll
        for (int a = 0; a < 5; ++a) acc[a] = fmaf(wa[q], As[a][n], acc[a]);
      }
    }
#pragma unroll
    for (int d = 1; d < 8; d <<= 1)
#pragma unroll
      for (int a = 0; a < 5; ++a) acc[a] += __shfl_xor(acc[a], d);
    if (ns == 0) {
#pragma unroll
      for (int a = 0; a < 5; ++a)
        McT[m * 40 + e * 5 + a] = (unsigned short)f2bf(acc[a]);
      if (e == 0)
#pragma unroll
        for (int r = 25; r < 40; ++r) McT[m * 40 + r] = 0;
    }
    return;
  }

  // ---- hist blocks: contiguous 1KB-per-wave reads ----
  const int idx2 = blockIdx.x - 20;
  const int b = idx2 >> 1, hh = idx2 & 1;
  const int w = t >> 6, l = t & 63;
  const int4* bp = (const int4*)bfm + (size_t)b * 4096 + hh * 2048;
  unsigned pA[4] = {0, 0, 0, 0}, pB[4] = {0, 0, 0, 0};
#pragma unroll
  for (int it = 0; it < 8; ++it) {
    const int4 v = bp[it * 256 + t];
    const int vv[4] = {v.x, v.y, v.z, v.w};
#pragma unroll
    for (int jj = 0; jj < 4; ++jj) {
      pA[jj] += (unsigned)(vv[jj] == 1) + ((unsigned)(vv[jj] == 2) << 8) +
                ((unsigned)(vv[jj] == 3) << 16) + ((unsigned)(vv[jj] == 4) << 24);
      pB[jj] += (unsigned)(vv[jj] == 5);
    }
  }
#pragma unroll
  for (int jj = 0; jj < 4; ++jj) {  // lanes l and l^32 share columns
    pA[jj] += (unsigned)__shfl_xor((int)pA[jj], 32);
    pB[jj] += (unsigned)__shfl_xor((int)pB[jj], 32);
  }
  if (l < 32) {
#pragma unroll
    for (int jj = 0; jj < 4; ++jj) {
      red[w][l][jj][0] = pA[jj];
      red[w][l][jj][1] = pB[jj];
    }
  }
  __syncthreads();
  if (t < 128) {
    unsigned A = 0, B = 0;
    const int cc = t >> 2, jj = t & 3;
#pragma unroll
    for (int w2 = 0; w2 < 4; ++w2) {
      A += red[w2][cc][jj][0];
      B += red[w2][cc][jj][1];
    }
    cnt_h[(b * 2 + hh) * 128 + t] = make_uint2(A, B);  // bytes <= 64
  }
}

// ---------------------------------------------------------------------------
// K2: out[b, h*64 .. +64, :] = (adj@P) @ McT, two skinny MFMA stages.
// 512 blocks (b, half) x 256 threads, ~23 KB LDS, 2 blocks/CU.
// Identical to r8 except stage-2 is operand-swapped (r10/r12-proven):
// lane holds 4 consecutive m -> 8 x f32x4 coalesced stores.
// ---------------------------------------------------------------------------
__global__ __launch_bounds__(256, 2) void skinny_kernel(
    const float* __restrict__ adj, const int* __restrict__ a_bfm,
    const uint2* __restrict__ cnt_h, const unsigned short* __restrict__ McT,
    float* __restrict__ out) {
  __shared__ __align__(16) unsigned short Pt[32 * 128];     // 8 KB, XOR-swz
  __shared__ __align__(16) unsigned short Mt[128 * 40];     // 10 KB
  __shared__ __align__(16) unsigned short Qs[4 * 16 * 40];  // 5 KB
  const int bh = blockIdx.x, b = bh >> 1, hh = bh & 1;
  const int t = threadIdx.x, w = t >> 6, l = t & 63, g = l >> 4, c = l & 15;
  const int row0 = hh * 64 + w * 16;

  // ---- T0: small loads first (consumed first), adj last (consumed last) ----
  uint2 h0 = make_uint2(0u, 0u), h1 = make_uint2(0u, 0u);
  int av = 0;
  if (t < 128) {
    h0 = cnt_h[(b * 2 + 0) * 128 + t];
    h1 = cnt_h[(b * 2 + 1) * 128 + t];
    av = a_bfm[b * 128 + t];
  }
  s16x8 mst0 = *(const s16x8*)&McT[t * 8];
  s16x8 mst1 = *(const s16x8*)&McT[(256 + t) * 8];
  s16x8 mst2 = {0, 0, 0, 0, 0, 0, 0, 0};
  if (t < 128) mst2 = *(const s16x8*)&McT[(512 + t) * 8];
  const float* arow = adj + (size_t)b * 16384 + (size_t)(row0 + c) * 128;
  float4 a0[4], a1[4];
#pragma unroll
  for (int kk = 0; kk < 4; ++kk) {
    a0[kk] = *(const float4*)(arow + kk * 32 + g * 8);
    a1[kk] = *(const float4*)(arow + kk * 32 + g * 8 + 4);
  }

  // ---- zero Pt; stage Mt (vmcnt waits only to mst; adj stays queued) ----
  ((uint4*)Pt)[t] = make_uint4(0u, 0u, 0u, 0u);
  ((uint4*)Pt)[256 + t] = make_uint4(0u, 0u, 0u, 0u);
  *(s16x8*)&Mt[t * 8] = mst0;
  *(s16x8*)&Mt[(256 + t) * 8] = mst1;
  if (t < 128) *(s16x8*)&Mt[(512 + t) * 8] = mst2;
  asm volatile("s_waitcnt lgkmcnt(0)" ::: "memory");
  __builtin_amdgcn_s_barrier();

  // ---- scatter P^T: Pt[r][j=t] = cnt_e(j), r=(e-1)*5+ai, XOR-swz chunks ----
  if (t < 128 && av > 0) {
    const unsigned cx = h0.x + h1.x;  // byte-packed add, bytes <= 128
    const unsigned cy = h0.y + h1.y;
    const int ai = av - 1;
    const int chunk = t >> 3, off = t & 7;
    const float cf[5] = {(float)(cx & 255u), (float)((cx >> 8) & 255u),
                         (float)((cx >> 16) & 255u), (float)(cx >> 24),
                         (float)(cy & 255u)};
#pragma unroll
    for (int ei = 0; ei < 5; ++ei) {
      const int r = ei * 5 + ai;
      Pt[r * 128 + ((chunk ^ (r & 15)) << 3) + off] =
          (unsigned short)f2bf(cf[ei]);
    }
  }
  asm volatile("s_waitcnt lgkmcnt(0)" ::: "memory");
  __builtin_amdgcn_s_barrier();

  // ---- stage 1: Q = adj @ P  (2 col-tiles x 4 k-chunks = 8 MFMA) ----
  s16x8 bP[4][2];
#pragma unroll
  for (int kk = 0; kk < 4; ++kk)
#pragma unroll
    for (int ct = 0; ct < 2; ++ct) {
      const int r = ct * 16 + c;
      bP[kk][ct] = *(const s16x8*)&Pt[r * 128 + (((kk * 4 + g) ^ (r & 15)) << 3)];
    }
  // pack adj A-frags (vmcnt(0) lands here; loads issued at T0, well covered)
  s16x8 apk[4];
#pragma unroll
  for (int kk = 0; kk < 4; ++kk) {
    unsigned* pu = (unsigned*)&apk[kk];
    pu[0] = pk2(a0[kk].x, a0[kk].y);
    pu[1] = pk2(a0[kk].z, a0[kk].w);
    pu[2] = pk2(a1[kk].x, a1[kk].y);
    pu[3] = pk2(a1[kk].z, a1[kk].w);
  }
  f32x4 accQ[2] = {{0.f, 0.f, 0.f, 0.f}, {0.f, 0.f, 0.f, 0.f}};
#pragma unroll
  for (int kk = 0; kk < 4; ++kk)
#pragma unroll
    for (int ct = 0; ct < 2; ++ct)
      accQ[ct] = __builtin_amdgcn_mfma_f32_16x16x32_bf16(apk[kk], bP[kk][ct],
                                                         accQ[ct], 0, 0, 0);

  // ---- transpose Q through wave-local LDS (no cross-wave barrier) ----
  unsigned short* qsw = &Qs[w * 16 * 40];
#pragma unroll
  for (int ct = 0; ct < 2; ++ct)
#pragma unroll
    for (int q = 0; q < 4; ++q)
      qsw[(g * 4 + q) * 40 + ct * 16 + c] = (unsigned short)f2bf(accQ[ct][q]);
  const s16x8 aQ = *(const s16x8*)&qsw[c * 40 + g * 8];

  // ---- stage 2 (operand-swapped): lane (g,c) -> out[row0+c][mt*16+g*4..+3]
  float* ob = out + (size_t)b * 16384 + (size_t)(row0 + c) * 128;
#pragma unroll
  for (int mt = 0; mt < 8; ++mt) {
    const s16x8 aM = *(const s16x8*)&Mt[(mt * 16 + c) * 40 + g * 8];
    f32x4 acc2 = {0.f, 0.f, 0.f, 0.f};
    acc2 = __builtin_amdgcn_mfma_f32_16x16x32_bf16(aM, aQ, acc2, 0, 0, 0);
    *(f32x4*)(ob + mt * 16 + g * 4) = acc2;
  }
}

extern "C" void kernel_launch(void* const* d_in, const int* in_sizes, int n_in,
                              void* d_out, int out_size, void* d_ws,
                              size_t ws_size, hipStream_t stream) {
  // inputs: 0=afm(unused), 1=bfm, 2=a_bfm, 3=adj, 4=adj_w, 5=adj_a
  const int* bfm = (const int*)d_in[1];
  const int* a_bfm = (const int*)d_in[2];
  const float* adj = (const float*)d_in[3];
  const float* adj_w = (const float*)d_in[4];
  const float* adj_a = (const float*)d_in[5];
  float* out = (float*)d_out;

  unsigned short* McT = (unsigned short*)d_ws;   // 128*40 bf16 = 10.24 KB
  uint2* cnt_h = (uint2*)((char*)d_ws + 16384);  // 256*2*128*8B = 512 KB

  hist_mc_kernel<<<dim3(532), dim3(256), 0, stream>>>(bfm, adj_w, adj_a,
                                                      cnt_h, McT);
  skinny_kernel<<<dim3(512), dim3(256), 0, stream>>>(adj, a_bfm, cnt_h, McT,
                                                     out);
}

// Round 16
// 16.858 us; speedup vs baseline: 7.0446x; 1.0694x over previous
//
#include <hip/hip_runtime.h>

typedef short s16x8 __attribute__((ext_vector_type(8)));
typedef float f32x4 __attribute__((ext_vector_type(4)));
typedef int i32x4 __attribute__((ext_vector_type(4)));

__device__ __forceinline__ short f2bf(float f) {  // RNE f32->bf16
  union { float f; unsigned u; } cv;
  cv.f = f;
  unsigned u = cv.u;
  u = (u + 0x7FFFu + ((u >> 16) & 1u)) >> 16;
  return (short)u;
}
// pack two f32 -> bf16x2 by truncation (low elem = lo)
__device__ __forceinline__ unsigned pk2(float lo, float hi) {
  union { float f; unsigned u; } a, b;
  a.f = lo;
  b.f = hi;
  return (a.u >> 16) | (b.u & 0xFFFF0000u);
}

// ---------------------------------------------------------------------------
// K1 (r8-proven): blocks 0..19 = McT table (transposed):
//   McT[m*40 + e*5 + a] = bf16(sum_n W[e,m,n]*A[a,n]); rows [25,40) zeroed.
// blocks 20..531 = histogram (b, row-half): contiguous 32KB read (nt),
//   partial counts -> cnt_h[(b*2+h)*128 + j] (uint2, byte-packed, <=64).
// ---------------------------------------------------------------------------
__global__ __launch_bounds__(256, 4) void hist_mc_kernel(
    const int* __restrict__ bfm, const float* __restrict__ adj_w,
    const float* __restrict__ adj_a, uint2* __restrict__ cnt_h,
    unsigned short* __restrict__ McT) {
  __shared__ unsigned red[4][32][4][2];
  __shared__ float As[5][128];
  const int t = threadIdx.x;

  if (blockIdx.x < 20) {  // ---- McT blocks ----
    const int bi = blockIdx.x;
    const int e = bi >> 2, mg = bi & 3;
    for (int idx = t; idx < 640; idx += 256) As[idx >> 7][idx & 127] = adj_a[idx];
    __syncthreads();
    const int m = mg * 32 + (t >> 3), ns = t & 7;
    const float* W = adj_w + (size_t)e * 16384 + (size_t)m * 128 + ns * 16;
    float acc[5] = {0.f, 0.f, 0.f, 0.f, 0.f};
#pragma unroll
    for (int it = 0; it < 4; ++it) {
      const float4 wv = *(const float4*)(W + it * 4);
      const float wa[4] = {wv.x, wv.y, wv.z, wv.w};
#pragma unroll
      for (int q = 0; q < 4; ++q) {
        const int n = ns * 16 + it * 4 + q;
#pragma unroll
        for (int a = 0; a < 5; ++a) acc[a] = fmaf(wa[q], As[a][n], acc[a]);
      }
    }
#pragma unroll
    for (int d = 1; d < 8; d <<= 1)
#pragma unroll
      for (int a = 0; a < 5; ++a) acc[a] += __shfl_xor(acc[a], d);
    if (ns == 0) {
#pragma unroll
      for (int a = 0; a < 5; ++a)
        McT[m * 40 + e * 5 + a] = (unsigned short)f2bf(acc[a]);
      if (e == 0)
#pragma unroll
        for (int r = 25; r < 40; ++r) McT[m * 40 + r] = 0;
    }
    return;
  }

  // ---- hist blocks: contiguous 1KB-per-wave nontemporal reads ----
  const int idx2 = blockIdx.x - 20;
  const int b = idx2 >> 1, hh = idx2 & 1;
  const int w = t >> 6, l = t & 63;
  const i32x4* bp = (const i32x4*)bfm + (size_t)b * 4096 + hh * 2048;
  unsigned pA[4] = {0, 0, 0, 0}, pB[4] = {0, 0, 0, 0};
#pragma unroll
  for (int it = 0; it < 8; ++it) {
    const i32x4 v = __builtin_nontemporal_load(&bp[it * 256 + t]);
#pragma unroll
    for (int jj = 0; jj < 4; ++jj) {
      const int vj = v[jj];
      pA[jj] += (unsigned)(vj == 1) + ((unsigned)(vj == 2) << 8) +
                ((unsigned)(vj == 3) << 16) + ((unsigned)(vj == 4) << 24);
      pB[jj] += (unsigned)(vj == 5);
    }
  }
#pragma unroll
  for (int jj = 0; jj < 4; ++jj) {  // lanes l and l^32 share columns
    pA[jj] += (unsigned)__shfl_xor((int)pA[jj], 32);
    pB[jj] += (unsigned)__shfl_xor((int)pB[jj], 32);
  }
  if (l < 32) {
#pragma unroll
    for (int jj = 0; jj < 4; ++jj) {
      red[w][l][jj][0] = pA[jj];
      red[w][l][jj][1] = pB[jj];
    }
  }
  __syncthreads();
  if (t < 128) {
    unsigned A = 0, B = 0;
    const int cc = t >> 2, jj = t & 3;
#pragma unroll
    for (int w2 = 0; w2 < 4; ++w2) {
      A += red[w2][cc][jj][0];
      B += red[w2][cc][jj][1];
    }
    cnt_h[(b * 2 + hh) * 128 + t] = make_uint2(A, B);  // bytes <= 64
  }
}

// ---------------------------------------------------------------------------
// K2 (r8-proven): out[b, h*64 .. +64, :] = (adj@P) @ McT, two skinny MFMA
// stages. 512 blocks (b, half) x 256 threads, ~23 KB LDS.
// adj loads nontemporal (read-once stream); out stores nontemporal.
// ---------------------------------------------------------------------------
__global__ __launch_bounds__(256, 2) void skinny_kernel(
    const float* __restrict__ adj, const int* __restrict__ a_bfm,
    const uint2* __restrict__ cnt_h, const unsigned short* __restrict__ McT,
    float* __restrict__ out) {
  __shared__ __align__(16) unsigned short Pt[32 * 128];     // 8 KB, XOR-swz
  __shared__ __align__(16) unsigned short Mt[128 * 40];     // 10 KB
  __shared__ __align__(16) unsigned short Qs[4 * 16 * 40];  // 5 KB
  const int bh = blockIdx.x, b = bh >> 1, hh = bh & 1;
  const int t = threadIdx.x, w = t >> 6, l = t & 63, g = l >> 4, c = l & 15;
  const int row0 = hh * 64 + w * 16;

  // ---- T0: small loads first (consumed first), adj last (consumed last) ----
  uint2 h0 = make_uint2(0u, 0u), h1 = make_uint2(0u, 0u);
  int av = 0;
  if (t < 128) {
    h0 = cnt_h[(b * 2 + 0) * 128 + t];
    h1 = cnt_h[(b * 2 + 1) * 128 + t];
    av = a_bfm[b * 128 + t];
  }
  s16x8 mst0 = *(const s16x8*)&McT[t * 8];
  s16x8 mst1 = *(const s16x8*)&McT[(256 + t) * 8];
  s16x8 mst2 = {0, 0, 0, 0, 0, 0, 0, 0};
  if (t < 128) mst2 = *(const s16x8*)&McT[(512 + t) * 8];
  const float* arow = adj + (size_t)b * 16384 + (size_t)(row0 + c) * 128;
  f32x4 a0[4], a1[4];
#pragma unroll
  for (int kk = 0; kk < 4; ++kk) {
    a0[kk] = __builtin_nontemporal_load(
        (const f32x4*)(arow + kk * 32 + g * 8));
    a1[kk] = __builtin_nontemporal_load(
        (const f32x4*)(arow + kk * 32 + g * 8 + 4));
  }

  // ---- zero Pt; stage Mt (vmcnt waits only to mst; adj stays queued) ----
  ((uint4*)Pt)[t] = make_uint4(0u, 0u, 0u, 0u);
  ((uint4*)Pt)[256 + t] = make_uint4(0u, 0u, 0u, 0u);
  *(s16x8*)&Mt[t * 8] = mst0;
  *(s16x8*)&Mt[(256 + t) * 8] = mst1;
  if (t < 128) *(s16x8*)&Mt[(512 + t) * 8] = mst2;
  asm volatile("s_waitcnt lgkmcnt(0)" ::: "memory");
  __builtin_amdgcn_s_barrier();

  // ---- scatter P^T: Pt[r][j=t] = cnt_e(j), r=(e-1)*5+ai, XOR-swz chunks ----
  if (t < 128 && av > 0) {
    const unsigned cx = h0.x + h1.x;  // byte-packed add, bytes <= 128
    const unsigned cy = h0.y + h1.y;
    const int ai = av - 1;
    const int chunk = t >> 3, off = t & 7;
    const float cf[5] = {(float)(cx & 255u), (float)((cx >> 8) & 255u),
                         (float)((cx >> 16) & 255u), (float)(cx >> 24),
                         (float)(cy & 255u)};
#pragma unroll
    for (int ei = 0; ei < 5; ++ei) {
      const int r = ei * 5 + ai;
      Pt[r * 128 + ((chunk ^ (r & 15)) << 3) + off] =
          (unsigned short)f2bf(cf[ei]);
    }
  }
  asm volatile("s_waitcnt lgkmcnt(0)" ::: "memory");
  __builtin_amdgcn_s_barrier();

  // ---- stage 1: Q = adj @ P  (2 col-tiles x 4 k-chunks = 8 MFMA) ----
  s16x8 bP[4][2];
#pragma unroll
  for (int kk = 0; kk < 4; ++kk)
#pragma unroll
    for (int ct = 0; ct < 2; ++ct) {
      const int r = ct * 16 + c;
      bP[kk][ct] = *(const s16x8*)&Pt[r * 128 + (((kk * 4 + g) ^ (r & 15)) << 3)];
    }
  // pack adj A-frags (vmcnt(0) lands here; loads issued at T0, well covered)
  s16x8 apk[4];
#pragma unroll
  for (int kk = 0; kk < 4; ++kk) {
    unsigned* pu = (unsigned*)&apk[kk];
    pu[0] = pk2(a0[kk][0], a0[kk][1]);
    pu[1] = pk2(a0[kk][2], a0[kk][3]);
    pu[2] = pk2(a1[kk][0], a1[kk][1]);
    pu[3] = pk2(a1[kk][2], a1[kk][3]);
  }
  f32x4 accQ[2] = {{0.f, 0.f, 0.f, 0.f}, {0.f, 0.f, 0.f, 0.f}};
#pragma unroll
  for (int kk = 0; kk < 4; ++kk)
#pragma unroll
    for (int ct = 0; ct < 2; ++ct)
      accQ[ct] = __builtin_amdgcn_mfma_f32_16x16x32_bf16(apk[kk], bP[kk][ct],
                                                         accQ[ct], 0, 0, 0);

  // ---- transpose Q through wave-local LDS (no cross-wave barrier) ----
  unsigned short* qsw = &Qs[w * 16 * 40];
#pragma unroll
  for (int ct = 0; ct < 2; ++ct)
#pragma unroll
    for (int q = 0; q < 4; ++q)
      qsw[(g * 4 + q) * 40 + ct * 16 + c] = (unsigned short)f2bf(accQ[ct][q]);
  const s16x8 aQ = *(const s16x8*)&qsw[c * 40 + g * 8];

  // ---- stage 2: out = Q @ Mtab (8 col-tiles), nontemporal scalar stores ----
  float* ob = out + (size_t)b * 16384 + (size_t)row0 * 128;
#pragma unroll
  for (int mt = 0; mt < 8; ++mt) {
    const s16x8 bM = *(const s16x8*)&Mt[(mt * 16 + c) * 40 + g * 8];
    f32x4 acc2 = {0.f, 0.f, 0.f, 0.f};
    acc2 = __builtin_amdgcn_mfma_f32_16x16x32_bf16(aQ, bM, acc2, 0, 0, 0);
#pragma unroll
    for (int q = 0; q < 4; ++q)
      __builtin_nontemporal_store(acc2[q],
                                  &ob[(g * 4 + q) * 128 + mt * 16 + c]);
  }
}

extern "C" void kernel_launch(void* const* d_in, const int* in_sizes, int n_in,
                              void* d_out, int out_size, void* d_ws,
                              size_t ws_size, hipStream_t stream) {
  // inputs: 0=afm(unused), 1=bfm, 2=a_bfm, 3=adj, 4=adj_w, 5=adj_a
  const int* bfm = (const int*)d_in[1];
  const int* a_bfm = (const int*)d_in[2];
  const float* adj = (const float*)d_in[3];
  const float* adj_w = (const float*)d_in[4];
  const float* adj_a = (const float*)d_in[5];
  float* out = (float*)d_out;

  unsigned short* McT = (unsigned short*)d_ws;   // 128*40 bf16 = 10.24 KB
  uint2* cnt_h = (uint2*)((char*)d_ws + 16384);  // 256*2*128*8B = 512 KB

  hist_mc_kernel<<<dim3(532), dim3(256), 0, stream>>>(bfm, adj_w, adj_a,
                                                      cnt_h, McT);
  skinny_kernel<<<dim3(512), dim3(256), 0, stream>>>(adj, a_bfm, cnt_h, McT,
                                                     out);
}